// Round 2
// baseline (236.130 us; speedup 1.0000x reference)
//
#include <hip/hip_runtime.h>
#include <math.h>

// SparseGatedMLP: out[t,:] = sum_r (x[t]·Win[i]) * gelu_tanh(x[t]·Wgate[i]) * Wout[i,:]
//   tokens = 8192, D = 512, R = 32, HIDDEN = 131072, all f32.
// Memory-bound gather: ~1.6 GB of 2KB-row gathers per call.

constexpr int D = 512;
constexpr int R = 32;

__device__ __forceinline__ float dot4(const float4 a, const float4 b) {
    return a.x * b.x + a.y * b.y + a.z * b.z + a.w * b.w;
}

__global__ __launch_bounds__(256, 4)
void sgmlp_kernel(const float* __restrict__ x,
                  const int* __restrict__ indices,
                  const float* __restrict__ w_in,
                  const float* __restrict__ w_gate,
                  const float* __restrict__ w_out,
                  float* __restrict__ out)
{
    const int token = blockIdx.x;
    const int tid   = threadIdx.x;
    const int wave  = tid >> 6;
    const int lane  = tid & 63;

    __shared__ float s_acc[4][D];   // per-wave partial outputs

    // Per-lane element positions: two float4 chunks covering 512 floats/wave.
    const int e0 = lane * 4;          // elems [e0, e0+3]
    const int e1 = 256 + lane * 4;    // elems [e1, e1+3]

    const float* xr = x + (size_t)token * D;
    const float4 x0 = *reinterpret_cast<const float4*>(xr + e0);
    const float4 x1 = *reinterpret_cast<const float4*>(xr + e1);

    float4 acc0 = make_float4(0.f, 0.f, 0.f, 0.f);
    float4 acc1 = make_float4(0.f, 0.f, 0.f, 0.f);

    // Each wave handles 8 of this token's 32 rows. Hoist all 8 indices so
    // the compiler can pipeline gather address generation across iterations.
    const int* idx_t = indices + token * R + wave * (R / 4);
    size_t ixs[R / 4];
    #pragma unroll
    for (int j = 0; j < R / 4; ++j) ixs[j] = (size_t)idx_t[j];

    #pragma unroll 2
    for (int j = 0; j < R / 4; ++j) {
        const float* kin = w_in   + ixs[j] * D;
        const float* kgt = w_gate + ixs[j] * D;
        const float* vot = w_out  + ixs[j] * D;

        // Coalesced row gathers (1024B per wave per float4 load).
        const float4 a0 = *reinterpret_cast<const float4*>(kin + e0);
        const float4 a1 = *reinterpret_cast<const float4*>(kin + e1);
        const float4 g0 = *reinterpret_cast<const float4*>(kgt + e0);
        const float4 g1 = *reinterpret_cast<const float4*>(kgt + e1);
        // Issue value-row loads early; only consumed after the reduction,
        // so their latency hides under the shuffle chain.
        const float4 v0 = *reinterpret_cast<const float4*>(vot + e0);
        const float4 v1 = *reinterpret_cast<const float4*>(vot + e1);

        float pc = dot4(x0, a0) + dot4(x1, a1);
        float pg = dot4(x0, g0) + dot4(x1, g1);

        // 64-lane butterfly reduce; result lands in every lane.
        #pragma unroll
        for (int m = 32; m >= 1; m >>= 1) {
            pc += __shfl_xor(pc, m, 64);
            pg += __shfl_xor(pg, m, 64);
        }

        // gelu_tanh(pg) = 0.5*pg*(1 + tanh(0.79788456*(pg + 0.044715*pg^3)))
        const float t  = 0.7978845608028654f * (pg + 0.044715f * pg * pg * pg);
        const float c  = pc * (0.5f * pg * (1.0f + tanhf(t)));

        acc0.x += c * v0.x; acc0.y += c * v0.y;
        acc0.z += c * v0.z; acc0.w += c * v0.w;
        acc1.x += c * v1.x; acc1.y += c * v1.y;
        acc1.z += c * v1.z; acc1.w += c * v1.w;
    }

    // Wave partials -> LDS
    *reinterpret_cast<float4*>(&s_acc[wave][e0]) = acc0;
    *reinterpret_cast<float4*>(&s_acc[wave][e1]) = acc1;
    __syncthreads();

    // Cross-wave reduce: 256 threads x 2 elems each.
    const int e = tid * 2;
    float2 r = make_float2(0.f, 0.f);
    #pragma unroll
    for (int w = 0; w < 4; ++w) {
        r.x += s_acc[w][e];
        r.y += s_acc[w][e + 1];
    }
    *reinterpret_cast<float2*>(out + (size_t)token * D + e) = r;
}

extern "C" void kernel_launch(void* const* d_in, const int* in_sizes, int n_in,
                              void* d_out, int out_size, void* d_ws, size_t ws_size,
                              hipStream_t stream)
{
    const float* x      = (const float*)d_in[0];
    const int*   idx    = (const int*)  d_in[1];   // int32 per harness convention
    const float* w_in   = (const float*)d_in[2];
    const float* w_gate = (const float*)d_in[3];
    const float* w_out  = (const float*)d_in[4];
    float*       out    = (float*)d_out;

    const int n_tok = in_sizes[0] / D;   // 8192
    sgmlp_kernel<<<n_tok, 256, 0, stream>>>(x, idx, w_in, w_gate, w_out, out);
}